// Round 1
// baseline (9751.072 us; speedup 1.0000x reference)
//
#include <hip/hip_runtime.h>
#include <hip/hip_cooperative_groups.h>
#include <cmath>

namespace cg = cooperative_groups;

#define TSTEPS 128
#define NENVS  64
#define HID    1024
#define G3     3072
#define MROWS  8192   // T*N

// ---------------------------------------------------------------------------
// h0T[k][n] = hxs[n][k]   (65536 threads)
__global__ __launch_bounds__(256) void k_transpose_in(const float* __restrict__ src,
                                                      float* __restrict__ dst) {
  int i = blockIdx.x * 256 + threadIdx.x;   // 0..65535
  int k = i >> 6, n = i & 63;
  dst[i] = src[n * HID + k];
}

// out_tail[n][k] = hT[k][n]
__global__ __launch_bounds__(256) void k_transpose_out(const float* __restrict__ src,
                                                       float* __restrict__ dst) {
  int i = blockIdx.x * 256 + threadIdx.x;   // 0..65535
  int n = i >> 10, k = i & 1023;
  dst[i] = src[k * 64 + n];
}

// ---------------------------------------------------------------------------
// gi GEMM, computed transposed: C[m][nn] with m = gate-col (3072), nn = sample (8192)
// C = A(w_ih)[3072][1024] · B(x)[8192][1024]^T + b_ih[m]
__global__ __launch_bounds__(256) void k_gemm_gi(const float* __restrict__ A,
                                                 const float* __restrict__ B,
                                                 const float* __restrict__ bias,
                                                 float* __restrict__ C) {
  __shared__ float As[16][64];
  __shared__ float Bs[16][64];
  const int t  = threadIdx.x;
  const int tx = t & 15, ty = t >> 4;
  const int m0 = blockIdx.y * 64;
  const int n0 = blockIdx.x * 64;
  const int lr = t >> 2, lk = (t & 3) * 4;
  float acc[4][4] = {{0.f, 0.f, 0.f, 0.f}};
  const float* Ap = A + (size_t)(m0 + lr) * HID + lk;
  const float* Bp = B + (size_t)(n0 + lr) * HID + lk;
  for (int k0 = 0; k0 < HID; k0 += 16) {
    float4 av = *(const float4*)(Ap + k0);
    float4 bv = *(const float4*)(Bp + k0);
    __syncthreads();
    As[lk + 0][lr] = av.x; As[lk + 1][lr] = av.y; As[lk + 2][lr] = av.z; As[lk + 3][lr] = av.w;
    Bs[lk + 0][lr] = bv.x; Bs[lk + 1][lr] = bv.y; Bs[lk + 2][lr] = bv.z; Bs[lk + 3][lr] = bv.w;
    __syncthreads();
#pragma unroll
    for (int kk = 0; kk < 16; ++kk) {
      const float4 a4 = *(const float4*)&As[kk][ty * 4];
      const float4 b4 = *(const float4*)&Bs[kk][tx * 4];
      const float a[4] = {a4.x, a4.y, a4.z, a4.w};
      const float b[4] = {b4.x, b4.y, b4.z, b4.w};
#pragma unroll
      for (int i = 0; i < 4; ++i)
#pragma unroll
        for (int jj = 0; jj < 4; ++jj)
          acc[i][jj] = fmaf(a[i], b[jj], acc[i][jj]);
    }
  }
#pragma unroll
  for (int i = 0; i < 4; ++i) {
    const int m = m0 + ty * 4 + i;
    const float bm = bias[m];
    float4 v;
    v.x = acc[i][0] + bm; v.y = acc[i][1] + bm;
    v.z = acc[i][2] + bm; v.w = acc[i][3] + bm;
    *(float4*)(C + (size_t)m * MROWS + n0 + tx * 4) = v;
  }
}

// ---------------------------------------------------------------------------
// out GEMM: C[8192][1024] = relu(feat · w_out^T + b_out)
// feat rows m = t*64+n live in ysT[t][k][n]  -> A-tile is a contiguous copy.
__global__ __launch_bounds__(256) void k_gemm_out(const float* __restrict__ ysT,
                                                  const float* __restrict__ W,
                                                  const float* __restrict__ bias,
                                                  float* __restrict__ C) {
  __shared__ float As[16][64];
  __shared__ float Bs[16][64];
  const int t  = threadIdx.x;
  const int tx = t & 15, ty = t >> 4;
  const int my = blockIdx.y;            // time index = m-tile (m0 = my*64)
  const int n0 = blockIdx.x * 64;
  const int lr = t >> 2, lk = (t & 3) * 4;
  float acc[4][4] = {{0.f, 0.f, 0.f, 0.f}};
  const float4* Abase = (const float4*)(ysT + (size_t)my * (HID * 64));
  const float*  Bp    = W + (size_t)(n0 + lr) * HID + lk;
  for (int k0 = 0; k0 < HID; k0 += 16) {
    float4 av = Abase[k0 * 16 + t];     // contiguous [k][n] chunk, no transpose
    float4 bv = *(const float4*)(Bp + k0);
    __syncthreads();
    ((float4*)As)[t] = av;
    Bs[lk + 0][lr] = bv.x; Bs[lk + 1][lr] = bv.y; Bs[lk + 2][lr] = bv.z; Bs[lk + 3][lr] = bv.w;
    __syncthreads();
#pragma unroll
    for (int kk = 0; kk < 16; ++kk) {
      const float4 a4 = *(const float4*)&As[kk][ty * 4];
      const float4 b4 = *(const float4*)&Bs[kk][tx * 4];
      const float a[4] = {a4.x, a4.y, a4.z, a4.w};
      const float b[4] = {b4.x, b4.y, b4.z, b4.w};
#pragma unroll
      for (int i = 0; i < 4; ++i)
#pragma unroll
        for (int jj = 0; jj < 4; ++jj)
          acc[i][jj] = fmaf(a[i], b[jj], acc[i][jj]);
    }
  }
  const float4 bc = *(const float4*)(bias + n0 + tx * 4);
#pragma unroll
  for (int i = 0; i < 4; ++i) {
    const int m = my * 64 + ty * 4 + i;
    float4 v;
    v.x = fmaxf(acc[i][0] + bc.x, 0.f);
    v.y = fmaxf(acc[i][1] + bc.y, 0.f);
    v.z = fmaxf(acc[i][2] + bc.z, 0.f);
    v.w = fmaxf(acc[i][3] + bc.w, 0.f);
    *(float4*)(C + (size_t)m * HID + n0 + tx * 4) = v;
  }
}

// ---------------------------------------------------------------------------
// Cooperative scan: 256 blocks x 256 threads, one thread per (n, j).
// Block b covers all 64 envs x 4 columns (j = b*4+q), so w_hh is read once/step.
// h kept transposed [k][n]; ysT[t] doubles as the h history.
__global__ __launch_bounds__(256) void k_gru_scan(const float* __restrict__ giT,  // [3072][8192]
                                                  const float* __restrict__ done, // [8192]
                                                  const float* __restrict__ Whh,  // [3072][1024]
                                                  const float* __restrict__ bhh,  // [3072]
                                                  const float* __restrict__ h0T,  // [1024][64]
                                                  float* __restrict__ ysT) {      // [128][1024][64]
  cg::grid_group grid = cg::this_grid();
  __shared__ float hs[64][64];          // 16 KB chunk of h (transposed: [kk][n])
  const int t = threadIdx.x;
  const int n = t & 63;
  const int q = t >> 6;                 // 0..3
  const int j = blockIdx.x * 4 + q;     // 0..1023
  const float* wr = Whh + (size_t)j * HID;
  const float* wz = Whh + (size_t)(HID + j) * HID;
  const float* wn = Whh + (size_t)(2 * HID + j) * HID;
  const float br = bhh[j], bz = bhh[HID + j], bn = bhh[2 * HID + j];
  const float* giR = giT + (size_t)j * MROWS;
  const float* giZ = giT + (size_t)(HID + j) * MROWS;
  const float* giN = giT + (size_t)(2 * HID + j) * MROWS;

  for (int step = 0; step < TSTEPS; ++step) {
    const float* hprev = step ? (ysT + (size_t)(step - 1) * (HID * 64)) : h0T;
    const float m = 1.0f - done[step * 64 + n];
    float ar = 0.f, az = 0.f, an = 0.f;
    for (int k0 = 0; k0 < HID; k0 += 64) {
      __syncthreads();                  // previous chunk's reads complete
      {
        const float4* src = (const float4*)(hprev + k0 * 64);  // contiguous 16KB
        float4* dst = (float4*)&hs[0][0];
        dst[t]       = src[t];
        dst[t + 256] = src[t + 256];
        dst[t + 512] = src[t + 512];
        dst[t + 768] = src[t + 768];
      }
      __syncthreads();
#pragma unroll
      for (int kk = 0; kk < 64; kk += 4) {
        const float4 w1 = *(const float4*)(wr + k0 + kk);   // wave-uniform
        const float4 w2 = *(const float4*)(wz + k0 + kk);
        const float4 w3 = *(const float4*)(wn + k0 + kk);
        const float h0v = hs[kk + 0][n], h1v = hs[kk + 1][n];
        const float h2v = hs[kk + 2][n], h3v = hs[kk + 3][n];
        ar += h0v * w1.x + h1v * w1.y + h2v * w1.z + h3v * w1.w;
        az += h0v * w2.x + h1v * w2.y + h2v * w2.z + h3v * w2.w;
        an += h0v * w3.x + h1v * w3.y + h2v * w3.z + h3v * w3.w;
      }
    }
    // gates:  gh = m*dot + b_hh ;  h_masked enters the z*h term
    const int col = step * 64 + n;
    const float hr = m * ar + br;
    const float hz = m * az + bz;
    const float hn = m * an + bn;
    const float ir  = giR[col];
    const float iz  = giZ[col];
    const float in_ = giN[col];
    const float r  = 1.f / (1.f + __expf(-(ir + hr)));
    const float z  = 1.f / (1.f + __expf(-(iz + hz)));
    const float ng = tanhf(in_ + r * hn);
    const float hm = m * hprev[(size_t)j * 64 + n];
    const float hnew = (1.f - z) * ng + z * hm;
    ysT[(size_t)step * (HID * 64) + (size_t)j * 64 + n] = hnew;
    grid.sync();
  }
}

// ---------------------------------------------------------------------------
extern "C" void kernel_launch(void* const* d_in, const int* in_sizes, int n_in,
                              void* d_out, int out_size, void* d_ws, size_t ws_size,
                              hipStream_t stream) {
  (void)in_sizes; (void)n_in; (void)out_size; (void)ws_size;
  const float* x     = (const float*)d_in[0];   // [8192][1024]
  const float* hxs   = (const float*)d_in[1];   // [64][1024]
  const float* done  = (const float*)d_in[2];   // [8192]
  const float* w_ih  = (const float*)d_in[3];   // [3072][1024]
  const float* w_hh  = (const float*)d_in[4];   // [3072][1024]
  const float* b_ih  = (const float*)d_in[5];   // [3072]
  const float* b_hh  = (const float*)d_in[6];   // [3072]
  const float* w_out = (const float*)d_in[7];   // [1024][1024]
  const float* b_out = (const float*)d_in[8];   // [1024]
  float* out = (float*)d_out;                   // [8192][1024] ++ [64][1024]

  float* giT = (float*)d_ws;                    // 3072*8192 floats (100.7 MB)
  float* ysT = giT + (size_t)G3 * MROWS;        // 128*1024*64 floats (33.6 MB)
  float* h0T = ysT + (size_t)TSTEPS * HID * 64; // 65536 floats

  // 1) h0 transpose
  hipLaunchKernelGGL(k_transpose_in, dim3(256), dim3(256), 0, stream, hxs, h0T);
  // 2) gi = x·w_ih^T + b_ih, stored transposed [3072][8192]
  hipLaunchKernelGGL(k_gemm_gi, dim3(MROWS / 64, G3 / 64), dim3(256), 0, stream,
                     w_ih, x, b_ih, giT);
  // 3) cooperative GRU scan (128 steps, grid.sync between steps)
  {
    const float* giT_c = giT;
    const float* h0T_c = h0T;
    float* ysT_p = ysT;
    void* args[6] = { (void*)&giT_c, (void*)&done, (void*)&w_hh,
                      (void*)&b_hh, (void*)&h0T_c, (void*)&ysT_p };
    hipLaunchCooperativeKernel(reinterpret_cast<void*>(k_gru_scan),
                               dim3(256), dim3(256), args, 0, stream);
  }
  // 4) out = relu(feat·w_out^T + b_out)
  hipLaunchKernelGGL(k_gemm_out, dim3(HID / 64, TSTEPS), dim3(256), 0, stream,
                     ysT, w_out, b_out, out);
  // 5) h_last transpose into tail of d_out
  hipLaunchKernelGGL(k_transpose_out, dim3(256), dim3(256), 0, stream,
                     ysT + (size_t)(TSTEPS - 1) * HID * 64, out + (size_t)MROWS * HID);
}

// Round 2
// 5843.783 us; speedup vs baseline: 1.6686x; 1.6686x over previous
//
#include <hip/hip_runtime.h>
#include <hip/hip_bf16.h>
#include <hip/hip_cooperative_groups.h>
#include <cmath>

namespace cg = cooperative_groups;

#define TSTEPS 128
#define NENVS  64
#define HID    1024
#define G3     3072
#define MROWS  8192   // T*N

typedef short bf8 __attribute__((ext_vector_type(8)));   // 8 bf16 = 4 VGPRs
typedef float f4  __attribute__((ext_vector_type(4)));   // MFMA acc

static __device__ inline short f2bf(float f) {
  __hip_bfloat16 h = __float2bfloat16(f);   // RNE
  return *reinterpret_cast<short*>(&h);
}

// ---------------------------------------------------------------------------
// h0T[k][n] = hxs[n][k]
__global__ __launch_bounds__(256) void k_transpose_in(const float* __restrict__ src,
                                                      float* __restrict__ dst) {
  int i = blockIdx.x * 256 + threadIdx.x;   // 0..65535
  int k = i >> 6, n = i & 63;
  dst[i] = src[n * HID + k];
}

// hb0[n][k] = bf16(hxs[n][k])  (same layout, cast only)
__global__ __launch_bounds__(256) void k_cvt_h0(const float* __restrict__ src,
                                                unsigned short* __restrict__ dst) {
  int i = blockIdx.x * 256 + threadIdx.x;
  dst[i] = (unsigned short)f2bf(src[i]);
}

// out_tail[n][k] = hT[k][n]
__global__ __launch_bounds__(256) void k_transpose_out(const float* __restrict__ src,
                                                       float* __restrict__ dst) {
  int i = blockIdx.x * 256 + threadIdx.x;   // 0..65535
  int n = i >> 10, k = i & 1023;
  dst[i] = src[k * 64 + n];
}

// ---------------------------------------------------------------------------
// gi GEMM (fp32), computed transposed: C[m][nn], m = gate-col (3072), nn = sample
__global__ __launch_bounds__(256) void k_gemm_gi(const float* __restrict__ A,
                                                 const float* __restrict__ B,
                                                 const float* __restrict__ bias,
                                                 float* __restrict__ C) {
  __shared__ float As[16][64];
  __shared__ float Bs[16][64];
  const int t  = threadIdx.x;
  const int tx = t & 15, ty = t >> 4;
  const int m0 = blockIdx.y * 64;
  const int n0 = blockIdx.x * 64;
  const int lr = t >> 2, lk = (t & 3) * 4;
  float acc[4][4] = {{0.f, 0.f, 0.f, 0.f}};
  const float* Ap = A + (size_t)(m0 + lr) * HID + lk;
  const float* Bp = B + (size_t)(n0 + lr) * HID + lk;
  for (int k0 = 0; k0 < HID; k0 += 16) {
    float4 av = *(const float4*)(Ap + k0);
    float4 bv = *(const float4*)(Bp + k0);
    __syncthreads();
    As[lk + 0][lr] = av.x; As[lk + 1][lr] = av.y; As[lk + 2][lr] = av.z; As[lk + 3][lr] = av.w;
    Bs[lk + 0][lr] = bv.x; Bs[lk + 1][lr] = bv.y; Bs[lk + 2][lr] = bv.z; Bs[lk + 3][lr] = bv.w;
    __syncthreads();
#pragma unroll
    for (int kk = 0; kk < 16; ++kk) {
      const float4 a4 = *(const float4*)&As[kk][ty * 4];
      const float4 b4 = *(const float4*)&Bs[kk][tx * 4];
      const float a[4] = {a4.x, a4.y, a4.z, a4.w};
      const float b[4] = {b4.x, b4.y, b4.z, b4.w};
#pragma unroll
      for (int i = 0; i < 4; ++i)
#pragma unroll
        for (int jj = 0; jj < 4; ++jj)
          acc[i][jj] = fmaf(a[i], b[jj], acc[i][jj]);
    }
  }
#pragma unroll
  for (int i = 0; i < 4; ++i) {
    const int m = m0 + ty * 4 + i;
    const float bm = bias[m];
    float4 v;
    v.x = acc[i][0] + bm; v.y = acc[i][1] + bm;
    v.z = acc[i][2] + bm; v.w = acc[i][3] + bm;
    *(float4*)(C + (size_t)m * MROWS + n0 + tx * 4) = v;
  }
}

// ---------------------------------------------------------------------------
// out GEMM (fp32): C[8192][1024] = relu(feat · w_out^T + b_out); A from ysT[t][k][64]
__global__ __launch_bounds__(256) void k_gemm_out(const float* __restrict__ ysT,
                                                  const float* __restrict__ W,
                                                  const float* __restrict__ bias,
                                                  float* __restrict__ C) {
  __shared__ float As[16][64];
  __shared__ float Bs[16][64];
  const int t  = threadIdx.x;
  const int tx = t & 15, ty = t >> 4;
  const int my = blockIdx.y;            // time index
  const int n0 = blockIdx.x * 64;
  const int lr = t >> 2, lk = (t & 3) * 4;
  float acc[4][4] = {{0.f, 0.f, 0.f, 0.f}};
  const float4* Abase = (const float4*)(ysT + (size_t)my * (HID * 64));
  const float*  Bp    = W + (size_t)(n0 + lr) * HID + lk;
  for (int k0 = 0; k0 < HID; k0 += 16) {
    float4 av = Abase[k0 * 16 + t];
    float4 bv = *(const float4*)(Bp + k0);
    __syncthreads();
    ((float4*)As)[t] = av;
    Bs[lk + 0][lr] = bv.x; Bs[lk + 1][lr] = bv.y; Bs[lk + 2][lr] = bv.z; Bs[lk + 3][lr] = bv.w;
    __syncthreads();
#pragma unroll
    for (int kk = 0; kk < 16; ++kk) {
      const float4 a4 = *(const float4*)&As[kk][ty * 4];
      const float4 b4 = *(const float4*)&Bs[kk][tx * 4];
      const float a[4] = {a4.x, a4.y, a4.z, a4.w};
      const float b[4] = {b4.x, b4.y, b4.z, b4.w};
#pragma unroll
      for (int i = 0; i < 4; ++i)
#pragma unroll
        for (int jj = 0; jj < 4; ++jj)
          acc[i][jj] = fmaf(a[i], b[jj], acc[i][jj]);
    }
  }
  const float4 bc = *(const float4*)(bias + n0 + tx * 4);
#pragma unroll
  for (int i = 0; i < 4; ++i) {
    const int m = my * 64 + ty * 4 + i;
    float4 v;
    v.x = fmaxf(acc[i][0] + bc.x, 0.f);
    v.y = fmaxf(acc[i][1] + bc.y, 0.f);
    v.z = fmaxf(acc[i][2] + bc.z, 0.f);
    v.w = fmaxf(acc[i][3] + bc.w, 0.f);
    *(float4*)(C + (size_t)m * HID + n0 + tx * 4) = v;
  }
}

// ---------------------------------------------------------------------------
// MFMA GRU scan. 256 blocks x 256 threads (4 waves). Block b owns hidden units
// j = 4b..4b+3; its 16 MFMA N-cols = {r0..r3, z0..z3, n0..n3, pad x4}.
// Wave w = M-tile of 16 envs. w_hh (bf16) lives in 128 VGPRs/lane for the
// whole kernel — zero per-step weight traffic (R1's latency killer).
// h broadcast between steps as bf16 [env][k], double-buffered.
__global__ __launch_bounds__(256) void k_gru_mfma(
    const float* __restrict__ giT,          // [3072][8192]
    const float* __restrict__ done,         // [8192]
    const float* __restrict__ Whh,          // [3072][1024]
    const float* __restrict__ bhh,          // [3072]
    const float* __restrict__ h0T,          // [1024][64] fp32
    const unsigned short* __restrict__ hb0, // [64][1024] bf16 (h0)
    unsigned short* __restrict__ hb1,       // [64][1024] bf16 (buf)
    float* __restrict__ ysT) {              // [128][1024][64]
  cg::grid_group grid = cg::this_grid();
  __shared__ float Ls[4][16][17];           // per-wave C-tile scratch
  const int t    = threadIdx.x;
  const int wave = t >> 6, lane = t & 63;
  const int quad = lane >> 4, l16 = lane & 15;
  const int j0   = blockIdx.x * 4;
  const int m0g  = wave * 16;               // this wave's first env

  // epilogue identity: lane -> (env = l16, jj = quad)
  const int j = j0 + quad;                  // hidden unit handled in epilogue
  const float br = bhh[j], bz = bhh[HID + j], bn = bhh[2 * HID + j];

  // --- load w_hh fragments into registers (bf16), once ---
  bf8 Bfrag[32];
  {
    const int c = l16;                      // N-col: gate*4 + jj (c<12), else pad
    const int gate = c >> 2, jj = c & 3;
    const float* wrow = Whh + (size_t)(HID * gate + j0 + jj) * HID;
#pragma unroll
    for (int kk = 0; kk < 32; ++kk) {
      bf8 bv = {0, 0, 0, 0, 0, 0, 0, 0};
      if (c < 12) {
        const float* s = wrow + kk * 32 + quad * 8;
#pragma unroll
        for (int e = 0; e < 8; ++e) bv[e] = f2bf(s[e]);
      }
      Bfrag[kk] = bv;
    }
  }

  for (int step = 0; step < TSTEPS; ++step) {
    const unsigned short* hbr = (step & 1) ? hb1 : hb0;
    unsigned short*       hbw = (unsigned short*)((step & 1) ? hb0 : hb1);

    // A-frags straight from global bf16 h: lane reads h[m0g+l16][kk*32+quad*8 ..+7]
    const bf8* Arow = (const bf8*)(hbr + (size_t)(m0g + l16) * HID) + quad;
    f4 acc0 = {0.f, 0.f, 0.f, 0.f};
    f4 acc1 = {0.f, 0.f, 0.f, 0.f};
#pragma unroll
    for (int kk = 0; kk < 32; kk += 2) {    // two chains: halve dependent latency
      bf8 a0 = Arow[kk * 4];
      bf8 a1 = Arow[kk * 4 + 4];
      acc0 = __builtin_amdgcn_mfma_f32_16x16x32_bf16(a0, Bfrag[kk], acc0, 0, 0, 0);
      acc1 = __builtin_amdgcn_mfma_f32_16x16x32_bf16(a1, Bfrag[kk + 1], acc1, 0, 0, 0);
    }
    const f4 acc = acc0 + acc1;

    // C-frag: col=lane&15, row=quad*4+r  ->  LDS [env][col]
    float* L = &Ls[wave][0][0];
#pragma unroll
    for (int r = 0; r < 4; ++r) L[(quad * 4 + r) * 17 + l16] = acc[r];
    __syncthreads();

    // epilogue: lane covers (env=l16 in this M-tile, hidden unit j = j0+quad)
    const int envg = m0g + l16;
    const int col  = step * 64 + envg;
    const float m  = 1.0f - done[col];
    const float rr = L[l16 * 17 + quad];
    const float zz = L[l16 * 17 + 4 + quad];
    const float nn = L[l16 * 17 + 8 + quad];
    const float ir  = giT[(size_t)j * MROWS + col];
    const float iz  = giT[(size_t)(HID + j) * MROWS + col];
    const float in_ = giT[(size_t)(2 * HID + j) * MROWS + col];
    const float* hprevT = step ? (ysT + (size_t)(step - 1) * (HID * 64)) : h0T;
    const float hp = hprevT[(size_t)j * 64 + envg];
    const float hr = m * rr + br;            // dot(m*h, w) == m*dot(h, w)
    const float hz = m * zz + bz;
    const float hn = m * nn + bn;
    const float rg = 1.f / (1.f + __expf(-(ir + hr)));
    const float zg = 1.f / (1.f + __expf(-(iz + hz)));
    const float ng = tanhf(in_ + rg * hn);
    const float hnew = (1.f - zg) * ng + zg * (m * hp);
    ysT[(size_t)step * (HID * 64) + (size_t)j * 64 + envg] = hnew;
    hbw[(size_t)envg * HID + j] = (unsigned short)f2bf(hnew);
    grid.sync();                             // publish h for all blocks
  }
}

// ---------------------------------------------------------------------------
extern "C" void kernel_launch(void* const* d_in, const int* in_sizes, int n_in,
                              void* d_out, int out_size, void* d_ws, size_t ws_size,
                              hipStream_t stream) {
  (void)in_sizes; (void)n_in; (void)out_size; (void)ws_size;
  const float* x     = (const float*)d_in[0];   // [8192][1024]
  const float* hxs   = (const float*)d_in[1];   // [64][1024]
  const float* done  = (const float*)d_in[2];   // [8192]
  const float* w_ih  = (const float*)d_in[3];   // [3072][1024]
  const float* w_hh  = (const float*)d_in[4];   // [3072][1024]
  const float* b_ih  = (const float*)d_in[5];   // [3072]
  const float* b_hh  = (const float*)d_in[6];   // [3072]
  const float* w_out = (const float*)d_in[7];   // [1024][1024]
  const float* b_out = (const float*)d_in[8];   // [1024]
  float* out = (float*)d_out;                   // [8192][1024] ++ [64][1024]

  float* giT = (float*)d_ws;                        // 3072*8192 f32
  float* ysT = giT + (size_t)G3 * MROWS;            // 128*1024*64 f32
  float* h0T = ysT + (size_t)TSTEPS * HID * 64;     // 65536 f32
  unsigned short* hb0 = (unsigned short*)(h0T + 65536);  // 65536 bf16
  unsigned short* hb1 = hb0 + 65536;                     // 65536 bf16

  hipLaunchKernelGGL(k_transpose_in, dim3(256), dim3(256), 0, stream, hxs, h0T);
  hipLaunchKernelGGL(k_cvt_h0, dim3(256), dim3(256), 0, stream, hxs, hb0);
  hipLaunchKernelGGL(k_gemm_gi, dim3(MROWS / 64, G3 / 64), dim3(256), 0, stream,
                     w_ih, x, b_ih, giT);
  {
    const float* giT_c = giT;
    const float* h0T_c = h0T;
    const unsigned short* hb0_c = hb0;
    unsigned short* hb1_p = hb1;
    float* ysT_p = ysT;
    void* args[8] = { (void*)&giT_c, (void*)&done, (void*)&w_hh, (void*)&b_hh,
                      (void*)&h0T_c, (void*)&hb0_c, (void*)&hb1_p, (void*)&ysT_p };
    hipLaunchCooperativeKernel(reinterpret_cast<void*>(k_gru_mfma),
                               dim3(256), dim3(256), args, 0, stream);
  }
  hipLaunchKernelGGL(k_gemm_out, dim3(HID / 64, TSTEPS), dim3(256), 0, stream,
                     ysT, w_out, b_out, out);
  hipLaunchKernelGGL(k_transpose_out, dim3(256), dim3(256), 0, stream,
                     ysT + (size_t)(TSTEPS - 1) * HID * 64, out + (size_t)MROWS * HID);
}

// Round 4
// 3683.797 us; speedup vs baseline: 2.6470x; 1.5863x over previous
//
#include <hip/hip_runtime.h>
#include <hip/hip_bf16.h>
#include <cmath>

#define TSTEPS 128
#define NENVS  64
#define HID    1024
#define G3     3072
#define MROWS  8192   // T*N

typedef unsigned short u16;
typedef short bf8 __attribute__((ext_vector_type(8)));   // 8 bf16 = 4 VGPRs
typedef float f4  __attribute__((ext_vector_type(4)));   // MFMA acc
typedef u16  us4  __attribute__((ext_vector_type(4)));

static __device__ inline u16 f2bf(float f) {
  __hip_bfloat16 h = __float2bfloat16(f);   // RNE
  return *reinterpret_cast<u16*>(&h);
}
static __device__ inline float bf2f(u16 v) {
  __hip_bfloat16 h = *reinterpret_cast<__hip_bfloat16*>(&v);
  return __bfloat162float(h);
}

// ---------------------------------------------------------------------------
// fp32 -> bf16 cast, 4 elements/thread
__global__ __launch_bounds__(256) void k_cast4(const float4* __restrict__ src,
                                               us4* __restrict__ dst, int n4) {
  int i = blockIdx.x * 256 + threadIdx.x;
  if (i < n4) {
    float4 v = src[i];
    us4 o = { f2bf(v.x), f2bf(v.y), f2bf(v.z), f2bf(v.w) };
    dst[i] = o;
  }
}

__global__ void k_zero1(unsigned* p) {
  if (threadIdx.x == 0 && blockIdx.x == 0) *p = 0u;
}

// out_tail[n][k] = float(featb_last[n][k])
__global__ __launch_bounds__(256) void k_tail(const u16* __restrict__ featb,
                                              float* __restrict__ dst) {
  int i = blockIdx.x * 256 + threadIdx.x;   // 0..65535
  dst[i] = bf2f(featb[(size_t)(TSTEPS - 1) * NENVS * HID + i]);
}

// ---------------------------------------------------------------------------
// Generic bf16 MFMA GEMM: C[M][N] = A[M][1024] · B[N][1024]^T + bias (+relu)
// 128x128 tile/block, 4 waves; wave = 32 m-rows x 128 n. Register double-buffer.
template<int BIAS_PER_N, int RELU>
__global__ __launch_bounds__(256, 2) void k_gemm_bf16(const u16* __restrict__ A,
                                                      const u16* __restrict__ B,
                                                      const float* __restrict__ bias,
                                                      float* __restrict__ C, int ldc) {
  const int t = threadIdx.x, wave = t >> 6, lane = t & 63;
  const int quad = lane >> 4, l16 = lane & 15;
  const int m0 = blockIdx.y * 128 + wave * 32;
  const int n0 = blockIdx.x * 128;
  const u16* Ap0 = A + (size_t)(m0 + l16) * HID + quad * 8;
  const u16* Ap1 = Ap0 + 16 * HID;
  const u16* Bp[8];
#pragma unroll
  for (int nt = 0; nt < 8; ++nt) Bp[nt] = B + (size_t)(n0 + nt * 16 + l16) * HID + quad * 8;

  f4 acc[2][8];
#pragma unroll
  for (int mt = 0; mt < 2; ++mt)
#pragma unroll
    for (int nt = 0; nt < 8; ++nt) acc[mt][nt] = (f4){0.f, 0.f, 0.f, 0.f};

  bf8 a_c[2], b_c[8], a_n[2], b_n[8];
  a_c[0] = *(const bf8*)Ap0;
  a_c[1] = *(const bf8*)Ap1;
#pragma unroll
  for (int nt = 0; nt < 8; ++nt) b_c[nt] = *(const bf8*)Bp[nt];

#pragma unroll
  for (int kk = 0; kk < 32; ++kk) {
    if (kk < 31) {
      const int off = (kk + 1) * 32;
      a_n[0] = *(const bf8*)(Ap0 + off);
      a_n[1] = *(const bf8*)(Ap1 + off);
#pragma unroll
      for (int nt = 0; nt < 8; ++nt) b_n[nt] = *(const bf8*)(Bp[nt] + off);
    }
#pragma unroll
    for (int mt = 0; mt < 2; ++mt)
#pragma unroll
      for (int nt = 0; nt < 8; ++nt)
        acc[mt][nt] = __builtin_amdgcn_mfma_f32_16x16x32_bf16(
            mt ? a_c[1] : a_c[0], b_c[nt], acc[mt][nt], 0, 0, 0);
    a_c[0] = a_n[0]; a_c[1] = a_n[1];
#pragma unroll
    for (int nt = 0; nt < 8; ++nt) b_c[nt] = b_n[nt];
  }

#pragma unroll
  for (int mt = 0; mt < 2; ++mt)
#pragma unroll
    for (int nt = 0; nt < 8; ++nt) {
      const int n = n0 + nt * 16 + l16;
      const float bn = BIAS_PER_N ? bias[n] : 0.f;
#pragma unroll
      for (int r = 0; r < 4; ++r) {
        const int m = m0 + mt * 16 + quad * 4 + r;
        float v = acc[mt][nt][r] + (BIAS_PER_N ? bn : bias[m]);
        if (RELU) v = fmaxf(v, 0.f);
        C[(size_t)m * ldc + n] = v;
      }
    }
}

// ---------------------------------------------------------------------------
// MFMA GRU scan with a memory-model-correct grid barrier.
// 256 blocks x 256 thr. Block owns hidden units j0..j0+3 (12 gate cols + 4 pad);
// wave = 16-env M-tile. w_hh bf16 fragments live in registers all 128 steps.
// h rows published per-step into featb (bf16) with agent-scope stores; the
// barrier does a proper agent release (waitcnt + L2 writeback) before arrive
// and agent acquire (buffer_inv) after — fixes R3's vmcnt-only race.
__global__ __launch_bounds__(256, 1) void k_gru_mfma(
    const float* __restrict__ giT,          // [3072][8192]
    const float* __restrict__ done,         // [8192]
    const float* __restrict__ Whh,          // [3072][1024]
    const float* __restrict__ bhh,          // [3072]
    const float* __restrict__ hxs,          // [64][1024] fp32
    const u16*  __restrict__ hb0,           // [64][1024] bf16 h0
    u16*        __restrict__ featb,         // [8192][1024] bf16 (per-step h rows)
    unsigned*   __restrict__ cnt) {         // barrier counter (init 0)
  __shared__ float Ls[4][16][17];
  const int t    = threadIdx.x;
  const int wave = t >> 6, lane = t & 63;
  const int quad = lane >> 4, l16 = lane & 15;
  const int j0   = blockIdx.x * 4;
  const int m0g  = wave * 16;               // this wave's first env

  // epilogue identity: env = l16 (within tile), hidden unit j = j0 + quad
  const int j = j0 + quad;
  const int envg = m0g + l16;
  const float br = bhh[j], bz = bhh[HID + j], bn = bhh[2 * HID + j];
  const float* giR = giT + (size_t)j * MROWS;
  const float* giZ = giT + (size_t)(HID + j) * MROWS;
  const float* giN = giT + (size_t)(2 * HID + j) * MROWS;
  float hp = hxs[(size_t)envg * HID + j];   // register-carried h_prev[j][env]

  // --- w_hh fragments -> registers (bf16), once ---
  bf8 Bfrag[32];
  {
    const int c = l16;                      // N-col: gate*4 + jj (c<12), else pad
    const int gate = c >> 2, jj = c & 3;
    const float* wrow = Whh + (size_t)(HID * gate + j0 + jj) * HID;
#pragma unroll
    for (int kk = 0; kk < 32; ++kk) {
      bf8 bv = {0, 0, 0, 0, 0, 0, 0, 0};
      if (c < 12) {
        const float* s = wrow + kk * 32 + quad * 8;
#pragma unroll
        for (int e = 0; e < 8; ++e) bv[e] = (short)f2bf(s[e]);
      }
      Bfrag[kk] = bv;
    }
  }

  for (int step = 0; step < TSTEPS; ++step) {
    const u16* hsrc = step ? (featb + (size_t)(step - 1) * (NENVS * HID)) : hb0;
    const bf8* Arow = (const bf8*)(hsrc + (size_t)envg * HID) + quad;

    // issue all 32 A-frag loads (normal cached; fresh after acquire-inv)
    bf8 ar[32];
#pragma unroll
    for (int kk = 0; kk < 32; ++kk) ar[kk] = Arow[kk * 4];

    // gi/done for this step (latency hidden under A-load wait + MFMA)
    const int col = step * 64 + envg;
    const float ir  = giR[col];
    const float iz  = giZ[col];
    const float in_ = giN[col];
    const float dn  = done[col];

    f4 acc0 = {0.f, 0.f, 0.f, 0.f};
    f4 acc1 = {0.f, 0.f, 0.f, 0.f};
#pragma unroll
    for (int kk = 0; kk < 32; kk += 2) {
      acc0 = __builtin_amdgcn_mfma_f32_16x16x32_bf16(ar[kk],     Bfrag[kk],     acc0, 0, 0, 0);
      acc1 = __builtin_amdgcn_mfma_f32_16x16x32_bf16(ar[kk + 1], Bfrag[kk + 1], acc1, 0, 0, 0);
    }
    const f4 acc = acc0 + acc1;

    // C-frag (row=env=quad*4+r, col=gatecol=l16) -> LDS (same-wave exchange)
    float* L = &Ls[wave][0][0];
#pragma unroll
    for (int r = 0; r < 4; ++r) L[(quad * 4 + r) * 17 + l16] = acc[r];
    const float m  = 1.0f - dn;
    const float rr = L[l16 * 17 + quad];
    const float zz = L[l16 * 17 + 4 + quad];
    const float nn = L[l16 * 17 + 8 + quad];
    const float hr = m * rr + br;            // dot(m*h,w) == m*dot(h,w)
    const float hz = m * zz + bz;
    const float hn = m * nn + bn;
    const float rg = 1.f / (1.f + __expf(-(ir + hr)));
    const float zg = 1.f / (1.f + __expf(-(iz + hz)));
    const float ng = tanhf(in_ + rg * hn);
    const float hnew = (1.f - zg) * ng + zg * (m * hp);
    hp = hnew;

    // publish h (agent-scope store; release fence below makes it visible)
    __hip_atomic_store(featb + (size_t)(step * 64 + envg) * HID + j,
                       f2bf(hnew), __ATOMIC_RELAXED, __HIP_MEMORY_SCOPE_AGENT);

    if (step != TSTEPS - 1) {
      // --- grid barrier with proper agent release/acquire ---
      __builtin_amdgcn_fence(__ATOMIC_RELEASE, "agent");  // waitcnt + L2 wb (per wave)
      __syncthreads();                                    // whole block released
      if (t == 0) {
        __hip_atomic_fetch_add(cnt, 1u, __ATOMIC_RELAXED, __HIP_MEMORY_SCOPE_AGENT);
        const unsigned tgt = 256u * (unsigned)(step + 1);
        while (__hip_atomic_load(cnt, __ATOMIC_RELAXED, __HIP_MEMORY_SCOPE_AGENT) < tgt)
          __builtin_amdgcn_s_sleep(1);
      }
      __syncthreads();
      __builtin_amdgcn_fence(__ATOMIC_ACQUIRE, "agent");  // inv L1/L2 (per wave)
    }
  }
}

// ---------------------------------------------------------------------------
extern "C" void kernel_launch(void* const* d_in, const int* in_sizes, int n_in,
                              void* d_out, int out_size, void* d_ws, size_t ws_size,
                              hipStream_t stream) {
  (void)in_sizes; (void)n_in; (void)out_size; (void)ws_size;
  const float* x     = (const float*)d_in[0];   // [8192][1024]
  const float* hxs   = (const float*)d_in[1];   // [64][1024]
  const float* done  = (const float*)d_in[2];   // [8192]
  const float* w_ih  = (const float*)d_in[3];   // [3072][1024]
  const float* w_hh  = (const float*)d_in[4];   // [3072][1024]
  const float* b_ih  = (const float*)d_in[5];   // [3072]
  const float* b_hh  = (const float*)d_in[6];   // [3072]
  const float* w_out = (const float*)d_in[7];   // [1024][1024]
  const float* b_out = (const float*)d_in[8];   // [1024]
  float* out = (float*)d_out;                   // [8192][1024] ++ [64][1024]

  // ws layout (~126 MB): giT | xb(=featb later) | wihb | woutb | hb0 | cnt
  float* giT   = (float*)d_ws;
  u16*   xb    = (u16*)(giT + (size_t)G3 * MROWS);       // [8192][1024] bf16
  u16*   featb = xb;                                     // overlay after gi-GEMM
  u16*   wihb  = xb + (size_t)MROWS * HID;
  u16*   woutb = wihb + (size_t)G3 * HID;
  u16*   hb0   = woutb + (size_t)HID * HID;
  unsigned* cnt = (unsigned*)(hb0 + (size_t)NENVS * HID);

  // casts + barrier init
  k_cast4<<<dim3(MROWS * HID / 4 / 256), dim3(256), 0, stream>>>((const float4*)x, (us4*)xb, MROWS * HID / 4);
  k_cast4<<<dim3(G3 * HID / 4 / 256), dim3(256), 0, stream>>>((const float4*)w_ih, (us4*)wihb, G3 * HID / 4);
  k_cast4<<<dim3(HID * HID / 4 / 256), dim3(256), 0, stream>>>((const float4*)w_out, (us4*)woutb, HID * HID / 4);
  k_cast4<<<dim3(NENVS * HID / 4 / 256), dim3(256), 0, stream>>>((const float4*)hxs, (us4*)hb0, NENVS * HID / 4);
  k_zero1<<<dim3(1), dim3(1), 0, stream>>>(cnt);

  // gi = w_ih · x^T + b_ih  -> [3072][8192] fp32
  k_gemm_bf16<0, 0><<<dim3(MROWS / 128, G3 / 128), dim3(256), 0, stream>>>(
      wihb, xb, b_ih, giT, MROWS);

  // GRU scan (cooperative for co-residency; sync is our own barrier)
  {
    const float* giT_c = giT; const float* done_c = done; const float* whh_c = w_hh;
    const float* bhh_c = b_hh; const float* hxs_c = hxs;
    const u16* hb0_c = hb0; u16* featb_p = featb; unsigned* cnt_p = cnt;
    void* args[8] = { (void*)&giT_c, (void*)&done_c, (void*)&whh_c, (void*)&bhh_c,
                      (void*)&hxs_c, (void*)&hb0_c, (void*)&featb_p, (void*)&cnt_p };
    hipLaunchCooperativeKernel(reinterpret_cast<void*>(k_gru_mfma),
                               dim3(256), dim3(256), args, 0, stream);
  }

  // out = relu(feat · w_out^T + b_out) -> [8192][1024] fp32
  k_gemm_bf16<1, 1><<<dim3(HID / 128, MROWS / 128), dim3(256), 0, stream>>>(
      featb, woutb, b_out, out, HID);

  // h_last tail
  k_tail<<<dim3(256), dim3(256), 0, stream>>>(featb, out + (size_t)MROWS * HID);
}

// Round 6
// 1622.474 us; speedup vs baseline: 6.0100x; 2.2705x over previous
//
#include <hip/hip_runtime.h>
#include <hip/hip_bf16.h>
#include <cmath>

#define TSTEPS 128
#define NENVS  64
#define HID    1024
#define G3     3072
#define MROWS  8192   // T*N

typedef unsigned short u16;
typedef unsigned long long u64;
typedef short bf8 __attribute__((ext_vector_type(8)));   // 8 bf16 = 4 VGPRs
typedef float f4  __attribute__((ext_vector_type(4)));   // MFMA acc
typedef u16  us4  __attribute__((ext_vector_type(4)));

static __device__ inline u16 f2bf(float f) {
  __hip_bfloat16 h = __float2bfloat16(f);   // RNE
  return *reinterpret_cast<u16*>(&h);
}
static __device__ inline float bf2f(u16 v) {
  __hip_bfloat16 h = *reinterpret_cast<__hip_bfloat16*>(&v);
  return __bfloat162float(h);
}

// ---------------------------------------------------------------------------
// fp32 -> bf16 cast, 4 elements/thread
__global__ __launch_bounds__(256) void k_cast4(const float4* __restrict__ src,
                                               us4* __restrict__ dst, int n4) {
  int i = blockIdx.x * 256 + threadIdx.x;
  if (i < n4) {
    float4 v = src[i];
    us4 o = { f2bf(v.x), f2bf(v.y), f2bf(v.z), f2bf(v.w) };
    dst[i] = o;
  }
}

__global__ void k_zero1(unsigned* p) {
  if (threadIdx.x == 0 && blockIdx.x == 0) *p = 0u;
}

// out_tail[n][k] = float(featb_last[n][k])
__global__ __launch_bounds__(256) void k_tail(const u16* __restrict__ featb,
                                              float* __restrict__ dst) {
  __builtin_amdgcn_fence(__ATOMIC_ACQUIRE, "agent");   // defensive: kill stale lines
  int i = blockIdx.x * 256 + threadIdx.x;   // 0..65535
  dst[i] = bf2f(featb[(size_t)(TSTEPS - 1) * NENVS * HID + i]);
}

// ---------------------------------------------------------------------------
// Generic bf16 MFMA GEMM: C[M][N] = A[M][1024] · B[N][1024]^T + bias (+relu)
// 128x128 tile/block, 4 waves; wave = 32 m-rows x 128 n. Register double-buffer.
// CT = float (fp32 out) or u16 (bf16 out).
template<typename CT, int BIAS_PER_N, int RELU>
__global__ __launch_bounds__(256, 2) void k_gemm_bf16(const u16* __restrict__ A,
                                                      const u16* __restrict__ B,
                                                      const float* __restrict__ bias,
                                                      CT* __restrict__ C, int ldc) {
  __builtin_amdgcn_fence(__ATOMIC_ACQUIRE, "agent");   // defensive (cheap, once)
  const int t = threadIdx.x, wave = t >> 6, lane = t & 63;
  const int quad = lane >> 4, l16 = lane & 15;
  const int m0 = blockIdx.y * 128 + wave * 32;
  const int n0 = blockIdx.x * 128;
  const u16* Ap0 = A + (size_t)(m0 + l16) * HID + quad * 8;
  const u16* Ap1 = Ap0 + 16 * HID;
  const u16* Bp[8];
#pragma unroll
  for (int nt = 0; nt < 8; ++nt) Bp[nt] = B + (size_t)(n0 + nt * 16 + l16) * HID + quad * 8;

  f4 acc[2][8];
#pragma unroll
  for (int mt = 0; mt < 2; ++mt)
#pragma unroll
    for (int nt = 0; nt < 8; ++nt) acc[mt][nt] = (f4){0.f, 0.f, 0.f, 0.f};

  bf8 a_c[2], b_c[8], a_n[2], b_n[8];
  a_c[0] = *(const bf8*)Ap0;
  a_c[1] = *(const bf8*)Ap1;
#pragma unroll
  for (int nt = 0; nt < 8; ++nt) b_c[nt] = *(const bf8*)Bp[nt];

#pragma unroll
  for (int kk = 0; kk < 32; ++kk) {
    if (kk < 31) {
      const int off = (kk + 1) * 32;
      a_n[0] = *(const bf8*)(Ap0 + off);
      a_n[1] = *(const bf8*)(Ap1 + off);
#pragma unroll
      for (int nt = 0; nt < 8; ++nt) b_n[nt] = *(const bf8*)(Bp[nt] + off);
    }
#pragma unroll
    for (int mt = 0; mt < 2; ++mt)
#pragma unroll
      for (int nt = 0; nt < 8; ++nt)
        acc[mt][nt] = __builtin_amdgcn_mfma_f32_16x16x32_bf16(
            mt ? a_c[1] : a_c[0], b_c[nt], acc[mt][nt], 0, 0, 0);
    a_c[0] = a_n[0]; a_c[1] = a_n[1];
#pragma unroll
    for (int nt = 0; nt < 8; ++nt) b_c[nt] = b_n[nt];
  }

#pragma unroll
  for (int mt = 0; mt < 2; ++mt)
#pragma unroll
    for (int nt = 0; nt < 8; ++nt) {
      const int n = n0 + nt * 16 + l16;
      const float bn = BIAS_PER_N ? bias[n] : 0.f;
#pragma unroll
      for (int r = 0; r < 4; ++r) {
        const int m = m0 + mt * 16 + quad * 4 + r;
        float v = acc[mt][nt][r] + (BIAS_PER_N ? bn : bias[m]);
        if (RELU) v = fmaxf(v, 0.f);
        if constexpr (sizeof(CT) == 2)
          C[(size_t)m * ldc + n] = (CT)f2bf(v);
        else
          C[(size_t)m * ldc + n] = v;
      }
    }
}

// ---------------------------------------------------------------------------
// MFMA GRU scan, fence-free steady state:
//  WRITE path: h published via returning agent atomic_swap_b64 -> data lands at
//    the MALL (R5-proven: cross-XCD barrier counters work); vmcnt(0) before
//    arrive => globally visible.
//  READ path (R5's bug fixed): PLAIN cached loads of a PRISTINE featb region.
//    No cache anywhere holds those lines (never touched; start fence clears any
//    memset residue), so the L2 miss fills THROUGH the MALL -> post-swap data.
//    sc0/sc1 loads (R3/R5) read DRAM, missing the MALL -> deterministic stale.
//  Barrier: relaxed agent fetch_add + spin (R4-proven), no wbl2/inv per step.
__global__ __launch_bounds__(256, 1) void k_gru_mfma(
    const u16*  __restrict__ giTb,          // [3072][8192] bf16
    const float* __restrict__ done,         // [8192]
    const float* __restrict__ Whh,          // [3072][1024]
    const float* __restrict__ bhh,          // [3072]
    const float* __restrict__ hxs,          // [64][1024] fp32
    const u16*  __restrict__ hb0,           // [64][1024] bf16 h0
    u16*        __restrict__ featb,         // [8192][1024] bf16, PRISTINE region
    unsigned*   __restrict__ cnt) {         // barrier counter (init 0)
  __builtin_amdgcn_fence(__ATOMIC_ACQUIRE, "agent");   // once: drop any stale lines
  __shared__ float Ls[4][16][17];
  __shared__ u16 Lh[4][16][4];              // per-wave h gather for 8B publish
  const int t    = threadIdx.x;
  const int wave = t >> 6, lane = t & 63;
  const int quad = lane >> 4, l16 = lane & 15;
  const int j0   = blockIdx.x * 4;
  const int m0g  = wave * 16;               // this wave's first env

  // epilogue identity: env = l16 (within tile), hidden unit j = j0 + quad
  const int j = j0 + quad;
  const int envg = m0g + l16;
  const float br = bhh[j], bz = bhh[HID + j], bn = bhh[2 * HID + j];
  const u16* giR = giTb + (size_t)j * MROWS;
  const u16* giZ = giTb + (size_t)(HID + j) * MROWS;
  const u16* giN = giTb + (size_t)(2 * HID + j) * MROWS;
  float hp = hxs[(size_t)envg * HID + j];   // register-carried h_prev[j][env]

  // --- w_hh fragments -> registers (bf16), once ---
  bf8 Bfrag[32];
  {
    const int c = l16;                      // N-col: gate*4 + jj (c<12), else pad
    const int gate = c >> 2, jj = c & 3;
    const float* wrow = Whh + (size_t)(HID * gate + j0 + jj) * HID;
#pragma unroll
    for (int kk = 0; kk < 32; ++kk) {
      bf8 bv = {0, 0, 0, 0, 0, 0, 0, 0};
      if (c < 12) {
        const float* s = wrow + kk * 32 + quad * 8;
#pragma unroll
        for (int e = 0; e < 8; ++e) bv[e] = (short)f2bf(s[e]);
      }
      Bfrag[kk] = bv;
    }
  }

  for (int step = 0; step < TSTEPS; ++step) {
    const u16* hsrc = step ? (featb + (size_t)(step - 1) * (NENVS * HID)) : hb0;
    const bf8* Arow = (const bf8*)(hsrc + (size_t)envg * HID) + quad;

    // 32 plain cached A-frag loads (pristine lines -> miss -> fill via MALL)
    bf8 ar[32];
#pragma unroll
    for (int kk = 0; kk < 32; ++kk) ar[kk] = Arow[kk * 4];

    // gi/done for this step (immutable during scan; latency overlaps A-wait)
    const int col = step * 64 + envg;
    const float ir  = bf2f(giR[col]);
    const float iz  = bf2f(giZ[col]);
    const float in_ = bf2f(giN[col]);
    const float dn  = done[col];

    f4 acc0 = {0.f, 0.f, 0.f, 0.f};
    f4 acc1 = {0.f, 0.f, 0.f, 0.f};
#pragma unroll
    for (int kk = 0; kk < 32; kk += 2) {
      acc0 = __builtin_amdgcn_mfma_f32_16x16x32_bf16(ar[kk],     Bfrag[kk],     acc0, 0, 0, 0);
      acc1 = __builtin_amdgcn_mfma_f32_16x16x32_bf16(ar[kk + 1], Bfrag[kk + 1], acc1, 0, 0, 0);
    }
    const f4 acc = acc0 + acc1;

    // C-frag (row=env=quad*4+r, col=gatecol=l16) -> LDS (same-wave exchange)
    float* L = &Ls[wave][0][0];
#pragma unroll
    for (int r = 0; r < 4; ++r) L[(quad * 4 + r) * 17 + l16] = acc[r];
    const float m  = 1.0f - dn;
    const float rr = L[l16 * 17 + quad];
    const float zz = L[l16 * 17 + 4 + quad];
    const float nn = L[l16 * 17 + 8 + quad];
    const float hr = m * rr + br;            // dot(m*h,w) == m*dot(h,w)
    const float hz = m * zz + bz;
    const float hn = m * nn + bn;
    const float rg = 1.f / (1.f + __expf(-(ir + hr)));
    const float zg = 1.f / (1.f + __expf(-(iz + hz)));
    const float ng = tanhf(in_ + rg * hn);
    const float hnew = (1.f - zg) * ng + zg * (m * hp);
    hp = hnew;

    // --- publish h at the MALL via returning atomic swap (8B/env/block) ---
    Lh[wave][l16][quad] = f2bf(hnew);
    __builtin_amdgcn_wave_barrier();
    if (quad == 0) {
      const u64 hv = *(const u64*)&Lh[wave][l16][0];
      u64* dst = (u64*)(featb + (size_t)(step * 64 + m0g + l16) * HID + j0);
      u64 old = __hip_atomic_exchange(dst, hv, __ATOMIC_RELAXED, __HIP_MEMORY_SCOPE_AGENT);
      asm volatile("" :: "v"(old));          // keep returning form: ack = at MALL
    }

    if (step != TSTEPS - 1) {
      asm volatile("s_waitcnt vmcnt(0)" ::: "memory");   // swaps done at MALL
      __syncthreads();
      if (t == 0) {
        __hip_atomic_fetch_add(cnt, 1u, __ATOMIC_RELAXED, __HIP_MEMORY_SCOPE_AGENT);
        const unsigned tgt = 256u * (unsigned)(step + 1);
        while (__hip_atomic_load(cnt, __ATOMIC_RELAXED, __HIP_MEMORY_SCOPE_AGENT) < tgt)
          __builtin_amdgcn_s_sleep(1);
      }
      __syncthreads();
      asm volatile("" ::: "memory");         // compiler: no hoisting above barrier
    }
  }
}

// ---------------------------------------------------------------------------
extern "C" void kernel_launch(void* const* d_in, const int* in_sizes, int n_in,
                              void* d_out, int out_size, void* d_ws, size_t ws_size,
                              hipStream_t stream) {
  (void)in_sizes; (void)n_in; (void)out_size; (void)ws_size;
  const float* x     = (const float*)d_in[0];   // [8192][1024]
  const float* hxs   = (const float*)d_in[1];   // [64][1024]
  const float* done  = (const float*)d_in[2];   // [8192]
  const float* w_ih  = (const float*)d_in[3];   // [3072][1024]
  const float* w_hh  = (const float*)d_in[4];   // [3072][1024]
  const float* b_ih  = (const float*)d_in[5];   // [3072]
  const float* b_hh  = (const float*)d_in[6];   // [3072]
  const float* w_out = (const float*)d_in[7];   // [1024][1024]
  const float* b_out = (const float*)d_in[8];   // [1024]
  float* out = (float*)d_out;                   // [8192][1024] ++ [64][1024]

  // ws layout (~92.4 MB): giTb | xb | featb (PRISTINE) | wihb | woutb | hb0 | cnt
  u16* giTb  = (u16*)d_ws;                               // [3072][8192] bf16
  u16* xb    = giTb + (size_t)G3 * MROWS;                // [8192][1024] bf16
  u16* featb = xb + (size_t)MROWS * HID;                 // [8192][1024] bf16
  u16* wihb  = featb + (size_t)MROWS * HID;
  u16* woutb = wihb + (size_t)G3 * HID;
  u16* hb0   = woutb + (size_t)HID * HID;
  unsigned* cnt = (unsigned*)(hb0 + (size_t)NENVS * HID);

  // casts + barrier init
  k_cast4<<<dim3(MROWS * HID / 4 / 256), dim3(256), 0, stream>>>((const float4*)x, (us4*)xb, MROWS * HID / 4);
  k_cast4<<<dim3(G3 * HID / 4 / 256), dim3(256), 0, stream>>>((const float4*)w_ih, (us4*)wihb, G3 * HID / 4);
  k_cast4<<<dim3(HID * HID / 4 / 256), dim3(256), 0, stream>>>((const float4*)w_out, (us4*)woutb, HID * HID / 4);
  k_cast4<<<dim3(NENVS * HID / 4 / 256), dim3(256), 0, stream>>>((const float4*)hxs, (us4*)hb0, NENVS * HID / 4);
  k_zero1<<<dim3(1), dim3(1), 0, stream>>>(cnt);

  // gi = w_ih · x^T + b_ih  -> [3072][8192] bf16
  k_gemm_bf16<u16, 0, 0><<<dim3(MROWS / 128, G3 / 128), dim3(256), 0, stream>>>(
      wihb, xb, b_ih, giTb, MROWS);

  // GRU scan (cooperative for co-residency; sync is our own fence-free barrier)
  {
    const u16* giTb_c = giTb; const float* done_c = done; const float* whh_c = w_hh;
    const float* bhh_c = b_hh; const float* hxs_c = hxs;
    const u16* hb0_c = hb0; u16* featb_p = featb; unsigned* cnt_p = cnt;
    void* args[8] = { (void*)&giTb_c, (void*)&done_c, (void*)&whh_c, (void*)&bhh_c,
                      (void*)&hxs_c, (void*)&hb0_c, (void*)&featb_p, (void*)&cnt_p };
    hipLaunchCooperativeKernel(reinterpret_cast<void*>(k_gru_mfma),
                               dim3(256), dim3(256), args, 0, stream);
  }

  // out = relu(feat · w_out^T + b_out) -> [8192][1024] fp32
  k_gemm_bf16<float, 1, 1><<<dim3(HID / 128, MROWS / 128), dim3(256), 0, stream>>>(
      featb, woutb, b_out, out, HID);

  // h_last tail
  k_tail<<<dim3(256), dim3(256), 0, stream>>>(featb, out + (size_t)MROWS * HID);
}

// Round 7
// 1462.990 us; speedup vs baseline: 6.6652x; 1.1090x over previous
//
#include <hip/hip_runtime.h>
#include <hip/hip_bf16.h>
#include <cmath>

#define TSTEPS 128
#define NENVS  64
#define HID    1024
#define G3     3072
#define MROWS  8192   // T*N

typedef unsigned short u16;
typedef unsigned long long u64;
typedef short bf8 __attribute__((ext_vector_type(8)));   // 8 bf16 = 4 VGPRs
typedef float f4  __attribute__((ext_vector_type(4)));   // MFMA acc
typedef u16  us4  __attribute__((ext_vector_type(4)));

#define FLAG_STRIDE 32   // u32s between flags (128 B) — no same-line RMW collisions

static __device__ inline u16 f2bf(float f) {
  __hip_bfloat16 h = __float2bfloat16(f);   // RNE
  return *reinterpret_cast<u16*>(&h);
}
static __device__ inline float bf2f(u16 v) {
  __hip_bfloat16 h = *reinterpret_cast<__hip_bfloat16*>(&v);
  return __bfloat162float(h);
}

// ---------------------------------------------------------------------------
// fp32 -> bf16 cast, 4 elements/thread
__global__ __launch_bounds__(256) void k_cast4(const float4* __restrict__ src,
                                               us4* __restrict__ dst, int n4) {
  int i = blockIdx.x * 256 + threadIdx.x;
  if (i < n4) {
    float4 v = src[i];
    us4 o = { f2bf(v.x), f2bf(v.y), f2bf(v.z), f2bf(v.w) };
    dst[i] = o;
  }
}

// zero the flag array (8192 u32 = 32 KB); runtime's end-of-kernel writeback
// makes the zeros MALL/DRAM-visible before the scan (R6-proven via cnt).
__global__ __launch_bounds__(256) void k_zerofl(unsigned* __restrict__ p) {
  p[blockIdx.x * 256 + threadIdx.x] = 0u;
}

// out_tail[n][k] = float(featb_last[n][k])
__global__ __launch_bounds__(256) void k_tail(const u16* __restrict__ featb,
                                              float* __restrict__ dst) {
  __builtin_amdgcn_fence(__ATOMIC_ACQUIRE, "agent");   // defensive: kill stale lines
  int i = blockIdx.x * 256 + threadIdx.x;   // 0..65535
  dst[i] = bf2f(featb[(size_t)(TSTEPS - 1) * NENVS * HID + i]);
}

// ---------------------------------------------------------------------------
// Generic bf16 MFMA GEMM: C[M][N] = A[M][1024] · B[N][1024]^T + bias (+relu)
// 128x128 tile/block, 4 waves; wave = 32 m-rows x 128 n. Register double-buffer.
// CT = float (fp32 out) or u16 (bf16 out).
template<typename CT, int BIAS_PER_N, int RELU>
__global__ __launch_bounds__(256, 2) void k_gemm_bf16(const u16* __restrict__ A,
                                                      const u16* __restrict__ B,
                                                      const float* __restrict__ bias,
                                                      CT* __restrict__ C, int ldc) {
  __builtin_amdgcn_fence(__ATOMIC_ACQUIRE, "agent");   // defensive (cheap, once)
  const int t = threadIdx.x, wave = t >> 6, lane = t & 63;
  const int quad = lane >> 4, l16 = lane & 15;
  const int m0 = blockIdx.y * 128 + wave * 32;
  const int n0 = blockIdx.x * 128;
  const u16* Ap0 = A + (size_t)(m0 + l16) * HID + quad * 8;
  const u16* Ap1 = Ap0 + 16 * HID;
  const u16* Bp[8];
#pragma unroll
  for (int nt = 0; nt < 8; ++nt) Bp[nt] = B + (size_t)(n0 + nt * 16 + l16) * HID + quad * 8;

  f4 acc[2][8];
#pragma unroll
  for (int mt = 0; mt < 2; ++mt)
#pragma unroll
    for (int nt = 0; nt < 8; ++nt) acc[mt][nt] = (f4){0.f, 0.f, 0.f, 0.f};

  bf8 a_c[2], b_c[8], a_n[2], b_n[8];
  a_c[0] = *(const bf8*)Ap0;
  a_c[1] = *(const bf8*)Ap1;
#pragma unroll
  for (int nt = 0; nt < 8; ++nt) b_c[nt] = *(const bf8*)Bp[nt];

#pragma unroll
  for (int kk = 0; kk < 32; ++kk) {
    if (kk < 31) {
      const int off = (kk + 1) * 32;
      a_n[0] = *(const bf8*)(Ap0 + off);
      a_n[1] = *(const bf8*)(Ap1 + off);
#pragma unroll
      for (int nt = 0; nt < 8; ++nt) b_n[nt] = *(const bf8*)(Bp[nt] + off);
    }
#pragma unroll
    for (int mt = 0; mt < 2; ++mt)
#pragma unroll
      for (int nt = 0; nt < 8; ++nt)
        acc[mt][nt] = __builtin_amdgcn_mfma_f32_16x16x32_bf16(
            mt ? a_c[1] : a_c[0], b_c[nt], acc[mt][nt], 0, 0, 0);
    a_c[0] = a_n[0]; a_c[1] = a_n[1];
#pragma unroll
    for (int nt = 0; nt < 8; ++nt) b_c[nt] = b_n[nt];
  }

#pragma unroll
  for (int mt = 0; mt < 2; ++mt)
#pragma unroll
    for (int nt = 0; nt < 8; ++nt) {
      const int n = n0 + nt * 16 + l16;
      const float bn = BIAS_PER_N ? bias[n] : 0.f;
#pragma unroll
      for (int r = 0; r < 4; ++r) {
        const int m = m0 + mt * 16 + quad * 4 + r;
        float v = acc[mt][nt][r] + (BIAS_PER_N ? bn : bias[m]);
        if (RELU) v = fmaxf(v, 0.f);
        if constexpr (sizeof(CT) == 2)
          C[(size_t)m * ldc + n] = (CT)f2bf(v);
        else
          C[(size_t)m * ldc + n] = v;
      }
    }
}

// ---------------------------------------------------------------------------
// MFMA GRU scan, team-partitioned (envs are independent in the recurrence):
//  4 teams x 64 blocks; team tm owns envs tm*16..tm*16+15; block = 16 envs x
//  16 j (wave = 4 j). Team-local barrier via per-block flags 128 B apart:
//  arrival = returning agent atomic swap (parallel, no same-address RMW
//  serialization [R6's 256-arrival single counter]); detection = per-thread
//  agent atomic load + __syncthreads_and. Write/read h paths as in R6
//  (swap->MALL; pristine plain cached loads fill through MALL).
__global__ __launch_bounds__(256, 1) void k_gru_mfma(
    const u16*  __restrict__ giTb,          // [3072][8192] bf16
    const float* __restrict__ done,         // [8192]
    const float* __restrict__ Whh,          // [3072][1024]
    const float* __restrict__ bhh,          // [3072]
    const float* __restrict__ hxs,          // [64][1024] fp32
    const u16*  __restrict__ hb0,           // [64][1024] bf16 h0
    u16*        __restrict__ featb,         // [8192][1024] bf16, PRISTINE region
    unsigned*   __restrict__ flags) {       // [256*FLAG_STRIDE] u32, zeroed
  __builtin_amdgcn_fence(__ATOMIC_ACQUIRE, "agent");   // once: drop stale lines
  __shared__ float Ls[4][16][17];
  __shared__ u16 Lh[4][16][4];              // per-wave h gather for 8B publish
  const int t    = threadIdx.x;
  const int wave = t >> 6, lane = t & 63;
  const int quad = lane >> 4, l16 = lane & 15;
  const int b    = blockIdx.x;
  const int tm   = b & 3;                   // team 0..3
  const int jblk = b >> 2;                  // 0..63 within team
  const int j0   = jblk * 16;               // block's 16 hidden units
  const int jw   = j0 + wave * 4;           // wave's 4 hidden units
  const int env0 = tm * 16;                 // team's 16 envs

  // thread identity: env = env0 + l16, hidden unit j = jw + quad
  const int j = jw + quad;
  const int envg = env0 + l16;
  const float br = bhh[j], bz = bhh[HID + j], bn = bhh[2 * HID + j];
  const u16* giR = giTb + (size_t)j * MROWS;
  const u16* giZ = giTb + (size_t)(HID + j) * MROWS;
  const u16* giN = giTb + (size_t)(2 * HID + j) * MROWS;
  float hp = hxs[(size_t)envg * HID + j];   // register-carried h_prev[env][j]

  unsigned* myflag   = flags + (size_t)b * FLAG_STRIDE;
  unsigned* pollflag = flags + (size_t)(((t & 63) << 2) | tm) * FLAG_STRIDE; // team member (t&63)

  // --- w_hh fragments -> registers (bf16), once. N-cols: gate*4 + jj of jw..jw+3
  bf8 Bfrag[32];
  {
    const int c = l16;                      // c<12: gate=c>>2, jj=c&3; else pad
    const int gate = c >> 2, jj = c & 3;
    const float* wrow = Whh + (size_t)(HID * gate + jw + jj) * HID;
#pragma unroll
    for (int kk = 0; kk < 32; ++kk) {
      bf8 bv = {0, 0, 0, 0, 0, 0, 0, 0};
      if (c < 12) {
        const float* s = wrow + kk * 32 + quad * 8;
#pragma unroll
        for (int e = 0; e < 8; ++e) bv[e] = (short)f2bf(s[e]);
      }
      Bfrag[kk] = bv;
    }
  }

  // prefetched gi/done for step 0
  u16 girv = giR[envg], gizv = giZ[envg], ginv = giN[envg];
  float dnv = done[envg];

  for (int step = 0; step < TSTEPS; ++step) {
    const u16* hsrc = step ? (featb + (size_t)(step - 1) * (NENVS * HID)) : hb0;
    const bf8* Arow = (const bf8*)(hsrc + (size_t)envg * HID) + quad;

    // 32 plain cached A-frag loads (pristine lines -> miss -> fill via MALL)
    bf8 ar[32];
#pragma unroll
    for (int kk = 0; kk < 32; ++kk) ar[kk] = Arow[kk * 4];

    const float ir  = bf2f(girv);
    const float iz  = bf2f(gizv);
    const float in_ = bf2f(ginv);
    const float dn  = dnv;

    f4 acc0 = {0.f, 0.f, 0.f, 0.f};
    f4 acc1 = {0.f, 0.f, 0.f, 0.f};
#pragma unroll
    for (int kk = 0; kk < 32; kk += 2) {
      acc0 = __builtin_amdgcn_mfma_f32_16x16x32_bf16(ar[kk],     Bfrag[kk],     acc0, 0, 0, 0);
      acc1 = __builtin_amdgcn_mfma_f32_16x16x32_bf16(ar[kk + 1], Bfrag[kk + 1], acc1, 0, 0, 0);
    }
    const f4 acc = acc0 + acc1;

    // C-frag (row=env=quad*4+r, col=gatecol=l16) -> LDS (same-wave exchange)
    float* L = &Ls[wave][0][0];
#pragma unroll
    for (int r = 0; r < 4; ++r) L[(quad * 4 + r) * 17 + l16] = acc[r];
    const float m  = 1.0f - dn;
    const float rr = L[l16 * 17 + quad];
    const float zz = L[l16 * 17 + 4 + quad];
    const float nn = L[l16 * 17 + 8 + quad];
    const float hr = m * rr + br;            // dot(m*h,w) == m*dot(h,w)
    const float hz = m * zz + bz;
    const float hn = m * nn + bn;
    const float rg = 1.f / (1.f + __expf(-(ir + hr)));
    const float zg = 1.f / (1.f + __expf(-(iz + hz)));
    const float ng = tanhf(in_ + rg * hn);
    const float hnew = (1.f - zg) * ng + zg * (m * hp);
    hp = hnew;

    // prefetch next step's gi/done (drains under the same vmcnt(0) as h swaps)
    if (step + 1 < TSTEPS) {
      const int c2 = (step + 1) * 64 + envg;
      girv = giR[c2]; gizv = giZ[c2]; ginv = giN[c2]; dnv = done[c2];
    }

    // --- publish h at the MALL via returning atomic swap (8B/env/wave) ---
    Lh[wave][l16][quad] = f2bf(hnew);
    __builtin_amdgcn_wave_barrier();
    if (quad == 0) {
      const u64 hv = *(const u64*)&Lh[wave][l16][0];
      u64* dst = (u64*)(featb + (size_t)(step * 64 + env0 + l16) * HID + jw);
      u64 old = __hip_atomic_exchange(dst, hv, __ATOMIC_RELAXED, __HIP_MEMORY_SCOPE_AGENT);
      asm volatile("" :: "v"(old));          // keep returning form: ack = at MALL
    }

    if (step != TSTEPS - 1) {
      asm volatile("s_waitcnt vmcnt(0)" ::: "memory");   // h swaps done at MALL
      __syncthreads();                                   // all waves drained
      if (t == 0) {
        unsigned old = __hip_atomic_exchange(myflag, (unsigned)(step + 1),
                                             __ATOMIC_RELAXED, __HIP_MEMORY_SCOPE_AGENT);
        asm volatile("" :: "v"(old));
      }
      const unsigned tgt = (unsigned)(step + 1);
      int ok;
      do {
        unsigned v = __hip_atomic_load(pollflag, __ATOMIC_RELAXED, __HIP_MEMORY_SCOPE_AGENT);
        ok = __syncthreads_and((int)(v >= tgt));
      } while (!ok);
      asm volatile("" ::: "memory");         // no hoisting above the barrier
    }
  }
}

// ---------------------------------------------------------------------------
extern "C" void kernel_launch(void* const* d_in, const int* in_sizes, int n_in,
                              void* d_out, int out_size, void* d_ws, size_t ws_size,
                              hipStream_t stream) {
  (void)in_sizes; (void)n_in; (void)out_size; (void)ws_size;
  const float* x     = (const float*)d_in[0];   // [8192][1024]
  const float* hxs   = (const float*)d_in[1];   // [64][1024]
  const float* done  = (const float*)d_in[2];   // [8192]
  const float* w_ih  = (const float*)d_in[3];   // [3072][1024]
  const float* w_hh  = (const float*)d_in[4];   // [3072][1024]
  const float* b_ih  = (const float*)d_in[5];   // [3072]
  const float* b_hh  = (const float*)d_in[6];   // [3072]
  const float* w_out = (const float*)d_in[7];   // [1024][1024]
  const float* b_out = (const float*)d_in[8];   // [1024]
  float* out = (float*)d_out;                   // [8192][1024] ++ [64][1024]

  // ws layout (~92.5 MB): giTb | xb | featb (PRISTINE) | wihb | woutb | hb0 | flags
  u16* giTb  = (u16*)d_ws;                               // [3072][8192] bf16
  u16* xb    = giTb + (size_t)G3 * MROWS;                // [8192][1024] bf16
  u16* featb = xb + (size_t)MROWS * HID;                 // [8192][1024] bf16
  u16* wihb  = featb + (size_t)MROWS * HID;
  u16* woutb = wihb + (size_t)G3 * HID;
  u16* hb0   = woutb + (size_t)HID * HID;
  unsigned* flags = (unsigned*)(hb0 + (size_t)NENVS * HID);  // 256*32 u32

  // casts + flag init
  k_cast4<<<dim3(MROWS * HID / 4 / 256), dim3(256), 0, stream>>>((const float4*)x, (us4*)xb, MROWS * HID / 4);
  k_cast4<<<dim3(G3 * HID / 4 / 256), dim3(256), 0, stream>>>((const float4*)w_ih, (us4*)wihb, G3 * HID / 4);
  k_cast4<<<dim3(HID * HID / 4 / 256), dim3(256), 0, stream>>>((const float4*)w_out, (us4*)woutb, HID * HID / 4);
  k_cast4<<<dim3(NENVS * HID / 4 / 256), dim3(256), 0, stream>>>((const float4*)hxs, (us4*)hb0, NENVS * HID / 4);
  k_zerofl<<<dim3(256 * FLAG_STRIDE / 256), dim3(256), 0, stream>>>(flags);

  // gi = w_ih · x^T + b_ih  -> [3072][8192] bf16
  k_gemm_bf16<u16, 0, 0><<<dim3(MROWS / 128, G3 / 128), dim3(256), 0, stream>>>(
      wihb, xb, b_ih, giTb, MROWS);

  // GRU scan (cooperative for co-residency; sync is team-local flag barrier)
  {
    const u16* giTb_c = giTb; const float* done_c = done; const float* whh_c = w_hh;
    const float* bhh_c = b_hh; const float* hxs_c = hxs;
    const u16* hb0_c = hb0; u16* featb_p = featb; unsigned* flags_p = flags;
    void* args[8] = { (void*)&giTb_c, (void*)&done_c, (void*)&whh_c, (void*)&bhh_c,
                      (void*)&hxs_c, (void*)&hb0_c, (void*)&featb_p, (void*)&flags_p };
    hipLaunchCooperativeKernel(reinterpret_cast<void*>(k_gru_mfma),
                               dim3(256), dim3(256), args, 0, stream);
  }

  // out = relu(feat · w_out^T + b_out) -> [8192][1024] fp32
  k_gemm_bf16<float, 1, 1><<<dim3(HID / 128, MROWS / 128), dim3(256), 0, stream>>>(
      featb, woutb, b_out, out, HID);

  // h_last tail
  k_tail<<<dim3(256), dim3(256), 0, stream>>>(featb, out + (size_t)MROWS * HID);
}